// Round 6
// baseline (1606.764 us; speedup 1.0000x reference)
//
#include <hip/hip_runtime.h>

#define BB 64
#define TT 72
#define SS 72
#define EE 128
#define HH 256
#define VV 32000
#define KK 512

using f32x4  = __attribute__((ext_vector_type(4))) float;
using short8 = __attribute__((ext_vector_type(8))) short;

__device__ __forceinline__ unsigned short f2bf(float f) {
  unsigned u = __float_as_uint(f);
  unsigned r = (u + 0x7fffu + ((u >> 16) & 1u)) >> 16;
  return (unsigned short)r;
}
__device__ __forceinline__ float bf2f(unsigned short b) {
  return __uint_as_float(((unsigned)b) << 16);
}
__device__ __forceinline__ float sigm(float x) { return 1.f / (1.f + __expf(-x)); }
__device__ __forceinline__ float tanh_f(float x) { return 1.f - 2.f / (__expf(2.f * x) + 1.f); }

__device__ __forceinline__ float wsum(float v) {
  v += __shfl_xor(v, 1, 64);  v += __shfl_xor(v, 2, 64);  v += __shfl_xor(v, 4, 64);
  v += __shfl_xor(v, 8, 64);  v += __shfl_xor(v, 16, 64); v += __shfl_xor(v, 32, 64);
  return v;
}
__device__ __forceinline__ float wmax(float v) {
  v = fmaxf(v, __shfl_xor(v, 1, 64));  v = fmaxf(v, __shfl_xor(v, 2, 64));
  v = fmaxf(v, __shfl_xor(v, 4, 64));  v = fmaxf(v, __shfl_xor(v, 8, 64));
  v = fmaxf(v, __shfl_xor(v, 16, 64)); v = fmaxf(v, __shfl_xor(v, 32, 64));
  return v;
}
__device__ __forceinline__ void g2l16(const void* g, void* l) {
  __builtin_amdgcn_global_load_lds((const __attribute__((address_space(1))) void*)g,
                                   (__attribute__((address_space(3))) void*)l, 16, 0, 0);
}

__device__ __forceinline__ uint4 pack8(const float4 v0, const float4 v1) {
  uint4 o;
  o.x = f2bf(v0.x) | ((unsigned)f2bf(v0.y) << 16);
  o.y = f2bf(v0.z) | ((unsigned)f2bf(v0.w) << 16);
  o.z = f2bf(v1.x) | ((unsigned)f2bf(v1.y) << 16);
  o.w = f2bf(v1.z) | ((unsigned)f2bf(v1.w) << 16);
  return o;
}

// ------------------------------------------------------------------ prep:
// roles by blockIdx: [0,48) build Wt; [48,66) gather xembt; [66,256) cvt wlin16
// Wt layout: [kt 0..11][row 0..1023] 64B entries (32 k-values bf16);
//   k = kt*32+kk maps to Whh (kt<8) else Wih.
__global__ void prep_kernel(const int* __restrict__ tok, const float* __restrict__ emb,
                            const float* __restrict__ Wih, const float* __restrict__ Whh,
                            const float* __restrict__ Wlin,
                            uint4* __restrict__ Wt, uint4* __restrict__ xembt,
                            unsigned short* __restrict__ wlin16) {
  const int bid = blockIdx.x, tid = threadIdx.x;
  if (bid < 48) {
    const int id  = bid * 256 + tid;          // (kt,row), 12288 total
    const int kt  = id >> 10, row = id & 1023;
    const float* src = (kt < 8) ? (Whh + (size_t)row * HH + kt * 32)
                                : (Wih + (size_t)row * EE + (kt - 8) * 32);
#pragma unroll
    for (int q = 0; q < 4; ++q) {
      const float4 v0 = ((const float4*)src)[q * 2];
      const float4 v1 = ((const float4*)src)[q * 2 + 1];
      Wt[(size_t)id * 4 + q] = pack8(v0, v1);
    }
  } else if (bid < 66) {
    for (int e = (bid - 48) * 256 + tid; e < TT * 16 * 64; e += 18 * 256) {
      const int b = e & 63, kcx = (e >> 6) & 15, t = e >> 10;
      const int tk = tok[b * TT + t];
      const float4* s = (const float4*)(emb + (size_t)tk * EE + kcx * 8);
      xembt[e] = pack8(s[0], s[1]);
    }
  } else {
    const int n4 = (VV * KK) / 4;
    for (int i = (bid - 66) * 256 + tid; i < n4; i += 190 * 256) {
      float4 v = ((const float4*)Wlin)[i];
      ushort4 o;
      o.x = f2bf(v.x); o.y = f2bf(v.y); o.z = f2bf(v.z); o.w = f2bf(v.w);
      ((ushort4*)wlin16)[i] = o;
    }
  }
}

// ------------------------------------------------------------------ lstm:
// 4 independent blocks x 512 threads; block bk owns batches [16bk,16bk+16),
// computes ALL 256 j -> zero inter-block sync. gates^T(16b x 1024g) =
// hx(16b x 384k) @ Wt^T, W streamed from L2 as coalesced 1KB b-frags.
// Wave w owns gate-cols [128w,128w+128). Pointwise in LDS-gates -> regs;
// h written locally to LDS hx + hcat h-half. c stays fp32 in regs.
__launch_bounds__(512)
__global__ void lstm_kernel(const float* __restrict__ h0, const float* __restrict__ c0,
                            const float* __restrict__ bih, const float* __restrict__ bhh,
                            const uint4* __restrict__ Wt,
                            const uint4* __restrict__ xembt,
                            unsigned short* __restrict__ hcat) {
  __shared__ __align__(16) uint4 hx[48 * 16];     // 12288 B: kc<32 h (xor-swz), kc>=32 x
  __shared__ float gates[16 * 1028];              // 65792 B (stride 1028: 2-way free)

  const int bk  = blockIdx.x;
  const int bbase = bk * 16;
  const int tid = threadIdx.x;
  const int ln  = tid & 63, w = tid >> 6;
  const int n16 = ln & 15, kgrp = ln >> 4;

  // pointwise ownership: thread (pb = tid>>5 in 0..15, jg = tid&31), j = jg*8+u
  const int pb = tid >> 5, jg = tid & 31;

  float creg[8], biasr[4][8];
#pragma unroll
  for (int u = 0; u < 8; u += 4) {
    const float4 cv = *(const float4*)(c0 + (size_t)(bbase + pb) * HH + jg * 8 + u);
    creg[u] = cv.x; creg[u+1] = cv.y; creg[u+2] = cv.z; creg[u+3] = cv.w;
  }
#pragma unroll
  for (int g = 0; g < 4; ++g)
#pragma unroll
    for (int u = 0; u < 8; u += 4) {
      const float4 bi = *(const float4*)(bih + g * HH + jg * 8 + u);
      const float4 bh = *(const float4*)(bhh + g * HH + jg * 8 + u);
      biasr[g][u] = bi.x + bh.x; biasr[g][u+1] = bi.y + bh.y;
      biasr[g][u+2] = bi.z + bh.z; biasr[g][u+3] = bi.w + bh.w;
    }

  // h(0): entry (kc = tid>>4, lb = tid&15), xor-swizzled on batch index
  {
    const int kc = tid >> 4, lb = tid & 15;
    const float* src = h0 + (size_t)(bbase + lb) * HH + kc * 8;
    hx[kc * 16 + (lb ^ (kc & 15))] = pack8(((const float4*)src)[0], ((const float4*)src)[1]);
  }
  __syncthreads();

  for (int t = 0; t < TT; ++t) {
    // stage x[t] (4 waves, 1 g2l16 each: 4 kcx x 16 b per wave)
    if (w < 4) {
      const int e = (t * 16 + w * 4 + kgrp) * 64 + bbase + n16;
      g2l16(xembt + e, (char*)hx + (32 + w * 4) * 256);
    }
    __syncthreads();   // x + h(t) visible

    // ---- MFMA: acc[ct] (16 b x 16 g), b-frags streamed from Wt ----
    f32x4 acc[8] = {};
#pragma unroll
    for (int kt = 0; kt < 12; ++kt) {
      const int kc = kt * 4 + kgrp;
      const int beff = (kc < 32) ? (n16 ^ (kc & 15)) : n16;
      const short8 a = *(const short8*)&hx[kc * 16 + beff];
      const uint4* wp = Wt + (size_t)(kt * 1024 + w * 128 + n16) * 4 + kgrp;
#pragma unroll
      for (int ct = 0; ct < 8; ++ct) {
        const short8 b = *(const short8*)(wp + (size_t)ct * 64);
        acc[ct] = __builtin_amdgcn_mfma_f32_16x16x32_bf16(a, b, acc[ct], 0, 0, 0);
      }
    }

    // ---- acc -> gates LDS: row = batch = kgrp*4+r, col = w*128+ct*16+n16 ----
#pragma unroll
    for (int ct = 0; ct < 8; ++ct)
#pragma unroll
      for (int r = 0; r < 4; ++r)
        gates[(kgrp * 4 + r) * 1028 + w * 128 + ct * 16 + n16] = acc[ct][r];
    __syncthreads();

    // ---- pointwise: 8 cells (batch pb, j = jg*8..+8) ----
    {
      const float* gr = gates + pb * 1028 + jg * 8;
      float hh[8];
#pragma unroll
      for (int u = 0; u < 8; ++u) {
        const float iv = gr[u]       + biasr[0][u];
        const float fv = gr[256 + u] + biasr[1][u];
        const float gv = gr[512 + u] + biasr[2][u];
        const float ov = gr[768 + u] + biasr[3][u];
        const float cn = sigm(fv) * creg[u] + sigm(iv) * tanh_f(gv);
        creg[u] = cn;
        hh[u] = sigm(ov) * tanh_f(cn);
      }
      uint4 ph;
      ph.x = f2bf(hh[0]) | ((unsigned)f2bf(hh[1]) << 16);
      ph.y = f2bf(hh[2]) | ((unsigned)f2bf(hh[3]) << 16);
      ph.z = f2bf(hh[4]) | ((unsigned)f2bf(hh[5]) << 16);
      ph.w = f2bf(hh[6]) | ((unsigned)f2bf(hh[7]) << 16);
      hx[jg * 16 + (pb ^ (jg & 15))] = ph;                       // h(t+1) local
      ((uint4*)hcat)[(size_t)(t * 64 + bbase + pb) * 64 + jg] = ph;  // h-half
    }
    __syncthreads();   // gates reads done before next step's MFMA overwrites
  }
}

// ------------------------------------------------------------------ attention:
// parallel over (b, t-quarter); reads h (bf16) from hcat h-half, writes ctx-half.
__launch_bounds__(256)
__global__ void attn_kernel(const float* __restrict__ enc, const int* __restrict__ lens,
                            unsigned short* __restrict__ hcat) {
  __shared__ __align__(16) float enc_s[SS * HH];
  __shared__ __align__(16) float h_s[HH];
  __shared__ float at_s[SS];

  const int b   = blockIdx.x >> 2;
  const int tq  = blockIdx.x & 3;
  const int tid = threadIdx.x;
  const int wv  = tid >> 6, ln = tid & 63;
  const int len = lens[b];
  const unsigned int* hcatu = (const unsigned int*)hcat;

  {
    const float4* src = (const float4*)(enc + (size_t)b * SS * HH);
    float4* dst = (float4*)enc_s;
    for (int i = tid; i < SS * HH / 4; i += 256) dst[i] = src[i];
  }

  for (int ti = 0; ti < TT / 4; ++ti) {
    const int t = tq * (TT / 4) + ti;
    __syncthreads();
    if (tid < 128) {
      const unsigned int v = hcatu[(size_t)(t * 64 + b) * 256 + tid];
      h_s[tid * 2]     = bf2f((unsigned short)(v & 0xffff));
      h_s[tid * 2 + 1] = bf2f((unsigned short)(v >> 16));
    }
    __syncthreads();

    const float4 hv = ((const float4*)h_s)[ln];
    for (int s = wv; s < SS; s += 4) {
      const float4 ev = ((const float4*)(enc_s + s * HH))[ln];
      float p = hv.x * ev.x + hv.y * ev.y + hv.z * ev.z + hv.w * ev.w;
      p = wsum(p);
      if (ln == 0) at_s[s] = p * 0.0625f;
    }
    __syncthreads();
    if (wv == 0) {
      const float v0 = (ln < len) ? at_s[ln] : -3.0e38f;
      const bool has1 = (ln < 8) && (64 + ln < len);
      const float v1 = has1 ? at_s[64 + ln] : -3.0e38f;
      const float m = wmax(fmaxf(v0, v1));
      const float e0 = (ln < len) ? __expf(v0 - m) : 0.f;
      const float e1 = has1 ? __expf(v1 - m) : 0.f;
      const float inv = 1.f / wsum(e0 + e1);
      at_s[ln] = e0 * inv;
      if (ln < 8) at_s[64 + ln] = e1 * inv;
    }
    __syncthreads();
    float acc = 0.f;
#pragma unroll 8
    for (int s = 0; s < SS; ++s) acc += at_s[s] * enc_s[s * HH + tid];
    hcat[(size_t)(t * 64 + b) * KK + HH + tid] = f2bf(acc);
  }
}

// ------------------------------------------------------------------ vocab GEMM
// A = hcat rows m = t*64+b (contiguous 512); epilogue scatters to out[b][t][n].
__launch_bounds__(256)
__global__ void gemm_kernel(const unsigned short* __restrict__ A,
                            const unsigned short* __restrict__ Bw,
                            const float* __restrict__ blin,
                            float* __restrict__ out) {
  __shared__ __align__(16) unsigned short As[128 * 32];
  __shared__ __align__(16) unsigned short Bs[128 * 32];

  const int bid = blockIdx.x;
  const int mt = bid % 36;       // m fast: XCD round-robin keeps B n-slab L2-hot
  const int nt = bid / 36;
  const int m0 = mt * 128, n0 = nt * 128;
  const int tid = threadIdx.x;
  const int ln = tid & 63;
  const int w  = tid >> 6;
  const int wm = w >> 1, wn = w & 1;

  const char* Ab = (const char*)(A + (size_t)m0 * KK);
  const char* Bb = (const char*)(Bw + (size_t)n0 * KK);

  const int o0 = tid * 16;
  const int o1 = o0 + 4096;
  const int r0 = o0 >> 6, c0b = o0 & 63;
  const int r1 = o1 >> 6, c1b = o1 & 63;

  f32x4 acc[4][4] = {};

  float bs[4];
#pragma unroll
  for (int fn = 0; fn < 4; ++fn) bs[fn] = blin[n0 + wn * 64 + fn * 16 + (ln & 15)];

  for (int kt = 0; kt < 16; ++kt) {
    const int kb = kt * 64;
    g2l16(Ab + (size_t)r0 * (KK * 2) + kb + c0b, (char*)As + o0);
    g2l16(Ab + (size_t)r1 * (KK * 2) + kb + c1b, (char*)As + o1);
    g2l16(Bb + (size_t)r0 * (KK * 2) + kb + c0b, (char*)Bs + o0);
    g2l16(Bb + (size_t)r1 * (KK * 2) + kb + c1b, (char*)Bs + o1);
    __syncthreads();

    short8 af[4], bf[4];
#pragma unroll
    for (int f = 0; f < 4; ++f) {
      af[f] = *(const short8*)&As[(wm * 64 + f * 16 + (ln & 15)) * 32 + (ln >> 4) * 8];
      bf[f] = *(const short8*)&Bs[(wn * 64 + f * 16 + (ln & 15)) * 32 + (ln >> 4) * 8];
    }
#pragma unroll
    for (int fm = 0; fm < 4; ++fm)
#pragma unroll
      for (int fn = 0; fn < 4; ++fn)
        acc[fm][fn] = __builtin_amdgcn_mfma_f32_16x16x32_bf16(af[fm], bf[fn], acc[fm][fn], 0, 0, 0);
    __syncthreads();
  }

#pragma unroll
  for (int fm = 0; fm < 4; ++fm) {
    const int mrow = m0 + wm * 64 + fm * 16 + (ln >> 4) * 4;   // 4-aligned
    const int trow = mrow >> 6, brow = mrow & 63;              // same t for r=0..3
#pragma unroll
    for (int fn = 0; fn < 4; ++fn) {
      const int n = n0 + wn * 64 + fn * 16 + (ln & 15);
      float* cp = out + (size_t)(brow * TT + trow) * VV + n;
#pragma unroll
      for (int r = 0; r < 4; ++r) cp[(size_t)r * TT * VV] = acc[fm][fn][r] + bs[fn];
    }
  }
}

// ------------------------------------------------------------------
extern "C" void kernel_launch(void* const* d_in, const int* in_sizes, int n_in,
                              void* d_out, int out_size, void* d_ws, size_t ws_size,
                              hipStream_t stream) {
  const int*   tok  = (const int*)  d_in[0];
  const float* enc  = (const float*)d_in[1];
  const int*   lens = (const int*)  d_in[2];
  const float* h0   = (const float*)d_in[3];
  const float* c0   = (const float*)d_in[4];
  const float* emb  = (const float*)d_in[5];
  const float* Wih  = (const float*)d_in[6];
  const float* Whh  = (const float*)d_in[7];
  const float* bih  = (const float*)d_in[8];
  const float* bhh  = (const float*)d_in[9];
  const float* Wlin = (const float*)d_in[10];
  const float* blin = (const float*)d_in[11];

  char* ws = (char*)d_ws;
  unsigned short* wlin16 = (unsigned short*)(ws);               // 32,768,000 B
  unsigned short* hcat   = (unsigned short*)(ws + 32768000);    //  4,718,592 B  [t][b][512]
  uint4*          xembt  = (uint4*)         (ws + 37486592);    //  1,179,648 B  [t][16][64]
  uint4*          Wt     = (uint4*)         (ws + 38666240);    //    786,432 B  [12][1024]x64B
  float* out = (float*)d_out;

  prep_kernel<<<256, 256, 0, stream>>>(tok, emb, Wih, Whh, Wlin, Wt, xembt, wlin16);
  lstm_kernel<<<4, 512, 0, stream>>>(h0, c0, bih, bhh, Wt, xembt, hcat);
  attn_kernel<<<BB * 4, 256, 0, stream>>>(enc, lens, hcat);
  gemm_kernel<<<36 * 250, 256, 0, stream>>>(hcat, wlin16, blin, out);
}

// Round 7
// 611.813 us; speedup vs baseline: 2.6262x; 2.6262x over previous
//
#include <hip/hip_runtime.h>

#define BB 64
#define TT 72
#define SS 72
#define EE 128
#define HH 256
#define VV 32000
#define KK 512
#define NB 4          // lstm blocks (one XCD)
#define NATTN 64      // attn blocks (one per batch)
#define NGEMM 188     // gemm blocks
#define NCHUNK 36     // 4608 / 128 rows
#define NNT 125       // 32000 / 256 cols
#define NITEM (NCHUNK * NNT)

using f32x4  = __attribute__((ext_vector_type(4))) float;
using short8 = __attribute__((ext_vector_type(8))) short;
typedef unsigned long long u64;

__device__ __forceinline__ unsigned short f2bf(float f) {
  unsigned u = __float_as_uint(f);
  unsigned r = (u + 0x7fffu + ((u >> 16) & 1u)) >> 16;
  return (unsigned short)r;
}
__device__ __forceinline__ float bf2f(unsigned short b) {
  return __uint_as_float(((unsigned)b) << 16);
}
__device__ __forceinline__ float sigm(float x) { return 1.f / (1.f + __expf(-x)); }
__device__ __forceinline__ float tanh_f(float x) { return 1.f - 2.f / (__expf(2.f * x) + 1.f); }

__device__ __forceinline__ float wsum(float v) {
  v += __shfl_xor(v, 1, 64);  v += __shfl_xor(v, 2, 64);  v += __shfl_xor(v, 4, 64);
  v += __shfl_xor(v, 8, 64);  v += __shfl_xor(v, 16, 64); v += __shfl_xor(v, 32, 64);
  return v;
}
__device__ __forceinline__ float wmax(float v) {
  v = fmaxf(v, __shfl_xor(v, 1, 64));  v = fmaxf(v, __shfl_xor(v, 2, 64));
  v = fmaxf(v, __shfl_xor(v, 4, 64));  v = fmaxf(v, __shfl_xor(v, 8, 64));
  v = fmaxf(v, __shfl_xor(v, 16, 64)); v = fmaxf(v, __shfl_xor(v, 32, 64));
  return v;
}
__device__ __forceinline__ void g2l16(const void* g, void* l) {
  __builtin_amdgcn_global_load_lds((const __attribute__((address_space(1))) void*)g,
                                   (__attribute__((address_space(3))) void*)l, 16, 0, 0);
}
__device__ __forceinline__ uint4 pack8(const float4 v0, const float4 v1) {
  uint4 o;
  o.x = f2bf(v0.x) | ((unsigned)f2bf(v0.y) << 16);
  o.y = f2bf(v0.z) | ((unsigned)f2bf(v0.w) << 16);
  o.z = f2bf(v1.x) | ((unsigned)f2bf(v1.y) << 16);
  o.w = f2bf(v1.z) | ((unsigned)f2bf(v1.w) << 16);
  return o;
}
__device__ __forceinline__ u64 aload(const u64* p) {
  return __hip_atomic_load(p, __ATOMIC_RELAXED, __HIP_MEMORY_SCOPE_AGENT);
}
__device__ __forceinline__ void astore(u64* p, u64 v) {
  __hip_atomic_store(p, v, __ATOMIC_RELAXED, __HIP_MEMORY_SCOPE_AGENT);
}

// ------------------------------------------------------------------ prep:
// blocks [0,18): gather xembt [t][kcx][b] 16B entries; [18,256): cvt wlin16
__global__ void prep_kernel(const int* __restrict__ tok, const float* __restrict__ emb,
                            const float* __restrict__ Wlin,
                            uint4* __restrict__ xembt, unsigned short* __restrict__ wlin16) {
  const int bid = blockIdx.x, tid = threadIdx.x;
  if (bid < 18) {
    for (int e = bid * 256 + tid; e < TT * 16 * 64; e += 18 * 256) {
      const int b = e & 63, kcx = (e >> 6) & 15, t = e >> 10;
      const int tk = tok[b * TT + t];
      const float4* s = (const float4*)(emb + (size_t)tk * EE + kcx * 8);
      xembt[e] = pack8(s[0], s[1]);
    }
  } else {
    const int n4 = (VV * KK) / 4;
    for (int i = (bid - 18) * 256 + tid; i < n4; i += 238 * 256) {
      float4 v = ((const float4*)Wlin)[i];
      ushort4 o;
      o.x = f2bf(v.x); o.y = f2bf(v.y); o.z = f2bf(v.z); o.w = f2bf(v.w);
      ((ushort4*)wlin16)[i] = o;
    }
  }
}

// ------------------------------------------------------------------ mega:
// 256 blocks x 512 thr, LDS 114688 B => 1 block/CU => all blocks co-resident.
// Roles: 4 lstm (same-XCD elected, round-5 design), 64 attn (b each), 188 gemm.
// Cross-XCD data: producer atomic-store -> consumer atomic-load (proven r3);
// flags ordered by s_waitcnt vmcnt(0) before flag store.
__global__ __launch_bounds__(512) void mega_kernel(
    const float* __restrict__ h0, const float* __restrict__ c0,
    const float* __restrict__ Wih, const float* __restrict__ Whh,
    const float* __restrict__ bih, const float* __restrict__ bhh,
    const float* __restrict__ enc, const int* __restrict__ lens,
    const float* __restrict__ blin, const uint4* __restrict__ xembt,
    const unsigned short* __restrict__ wlin16,
    uint4* __restrict__ hex, unsigned int* __restrict__ sync,
    u64* __restrict__ hcat64, float* __restrict__ out) {
  __shared__ __align__(16) char smem[114688];
  __shared__ int s_role;

  const int tid = threadIdx.x;
  unsigned int* flags1 = sync;        // [0..3] lstm step counters
  unsigned int* F2     = sync + 8;    // [0..71] attn completion counters
  unsigned int* elect  = sync + 96;   // [0..7] arrivals, [8] winner, [9] roleCtr

  // ---- role election ----
  if (tid == 0) {
    unsigned xcd;
    asm volatile("s_getreg_b32 %0, hwreg(20, 0, 8)" : "=s"(xcd));
    xcd &= 7;
    int role = -1;
    const unsigned my = __hip_atomic_fetch_add(elect + xcd, 1u,
                          __ATOMIC_RELAXED, __HIP_MEMORY_SCOPE_AGENT);
    if (my < NB) {
      if (my == NB - 1) {
        unsigned exp = 0;
        __hip_atomic_compare_exchange_strong(elect + 8, &exp, xcd + 1,
            __ATOMIC_RELAXED, __ATOMIC_RELAXED, __HIP_MEMORY_SCOPE_AGENT);
      }
      unsigned wv;
      while ((wv = __hip_atomic_load(elect + 8, __ATOMIC_RELAXED,
                                     __HIP_MEMORY_SCOPE_AGENT)) == 0)
        __builtin_amdgcn_s_sleep(1);
      if (wv == xcd + 1) role = (int)my;
    }
    if (role < 0) {
      const unsigned idx = __hip_atomic_fetch_add(elect + 9, 1u,
                             __ATOMIC_RELAXED, __HIP_MEMORY_SCOPE_AGENT);
      role = (idx < NATTN) ? (100 + (int)idx) : (1000 + (int)(idx - NATTN));
    }
    s_role = role;
  }
  __syncthreads();
  const int role = s_role;

  if (role < NB) {
    // ============================ LSTM (round-5, verbatim + hcat h-half) ====
    const int bk = role;
    uint4* hx = (uint4*)smem;                // 48*64 entries (49152 B)
    uint4* xw = (uint4*)(smem + 49152);      // 4096 entries (65536 B)
    const int ln = tid & 63, w = tid >> 6;
    const int n16 = ln & 15, kgrp = ln >> 4;
    const int wj = w >> 1, wb = w & 1;
    u64* hexq = (u64*)hex;

    short8 wf[4][8];
    f32x4 biasf[4];
    {
      const int jrow = bk * 64 + wj * 16;
#pragma unroll
      for (int g = 0; g < 4; ++g) {
        const int row = g * HH + jrow + n16;
#pragma unroll
        for (int kt = 0; kt < 8; ++kt) {
          const float* src = Whh + (size_t)row * HH + kt * 32 + kgrp * 8;
          const float4 v0 = ((const float4*)src)[0];
          const float4 v1 = ((const float4*)src)[1];
          short8 wv;
          wv[0]=(short)f2bf(v0.x); wv[1]=(short)f2bf(v0.y); wv[2]=(short)f2bf(v0.z); wv[3]=(short)f2bf(v0.w);
          wv[4]=(short)f2bf(v1.x); wv[5]=(short)f2bf(v1.y); wv[6]=(short)f2bf(v1.z); wv[7]=(short)f2bf(v1.w);
          wf[g][kt] = wv;
        }
        const int r4 = g * HH + jrow + kgrp * 4;
        const float4 bi = *(const float4*)(bih + r4);
        const float4 bh = *(const float4*)(bhh + r4);
        biasf[g] = (f32x4){bi.x + bh.x, bi.y + bh.y, bi.z + bh.z, bi.w + bh.w};
      }
    }
#pragma unroll
    for (int i = 0; i < 8; ++i) {
      const int e = i * 512 + tid;
      const int en = e & 15, ek = (e >> 4) & 3, ewj = (e >> 6) & 3,
                ekt = (e >> 8) & 3, eg = e >> 10;
      const int row = eg * HH + bk * 64 + ewj * 16 + en;
      const float* src = Wih + (size_t)row * EE + ekt * 32 + ek * 8;
      xw[e] = pack8(((const float4*)src)[0], ((const float4*)src)[1]);
    }
    float creg[2][4];
#pragma unroll
    for (int mt = 0; mt < 2; ++mt)
#pragma unroll
      for (int r = 0; r < 4; ++r)
        creg[mt][r] = c0[(size_t)((wb * 2 + mt) * 16 + n16) * HH + bk * 64 + wj * 16 + kgrp * 4 + r];
#pragma unroll
    for (int i = 0; i < 4; ++i) {
      const int e = i * 512 + tid;
      const int kc = e >> 6, b = e & 63;
      const float* src = h0 + (size_t)b * HH + kc * 8;
      hx[kc * 64 + b] = pack8(((const float4*)src)[0], ((const float4*)src)[1]);
    }
    __syncthreads();

    const int kcq  = bk * 8 + wj * 2 + (kgrp >> 1);
    const int half = kgrp & 1;
    const int jq   = bk * 16 + wj * 4 + kgrp;     // hcat u64 col for j-quad

    for (int t = 0; t < TT; ++t) {
#pragma unroll
      for (int i = 0; i < 2; ++i) {
        const int e = (i * 8 + w) * 64 + ln;
        g2l16(xembt + (size_t)t * 1024 + e, (char*)&hx[32 * 64] + e * 16);
      }
      if (t > 0) {
        if (tid < NB) {
          while (__hip_atomic_load(flags1 + tid, __ATOMIC_RELAXED,
                                   __HIP_MEMORY_SCOPE_AGENT) < (unsigned)t)
            __builtin_amdgcn_s_sleep(1);
        }
        __syncthreads();
#pragma unroll
        for (int i = 0; i < 4; ++i) {
          const int e = (i * 8 + w) * 64 + ln;
          g2l16(hex + (size_t)t * 2048 + e, (char*)hx + e * 16);
        }
      }
      __syncthreads();   // drains vmcnt(0): hx staged

      f32x4 acc[4][2];
#pragma unroll
      for (int g = 0; g < 4; ++g)
#pragma unroll
        for (int mt = 0; mt < 2; ++mt)
          acc[g][mt] = biasf[g];

#pragma unroll
      for (int kt = 0; kt < 8; ++kt) {
#pragma unroll
        for (int mt = 0; mt < 2; ++mt) {
          const short8 b = *(const short8*)&hx[(kt * 4 + kgrp) * 64 + (wb * 2 + mt) * 16 + n16];
          acc[0][mt] = __builtin_amdgcn_mfma_f32_16x16x32_bf16(wf[0][kt], b, acc[0][mt], 0, 0, 0);
          acc[1][mt] = __builtin_amdgcn_mfma_f32_16x16x32_bf16(wf[1][kt], b, acc[1][mt], 0, 0, 0);
          acc[2][mt] = __builtin_amdgcn_mfma_f32_16x16x32_bf16(wf[2][kt], b, acc[2][mt], 0, 0, 0);
          acc[3][mt] = __builtin_amdgcn_mfma_f32_16x16x32_bf16(wf[3][kt], b, acc[3][mt], 0, 0, 0);
        }
      }
#pragma unroll
      for (int kti = 0; kti < 4; ++kti) {
        short8 wx[4];
#pragma unroll
        for (int g = 0; g < 4; ++g)
          wx[g] = *(const short8*)&xw[(((g * 4 + kti) * 4 + wj) * 4 + kgrp) * 16 + n16];
#pragma unroll
        for (int mt = 0; mt < 2; ++mt) {
          const short8 b = *(const short8*)&hx[(32 + kti * 4 + kgrp) * 64 + (wb * 2 + mt) * 16 + n16];
#pragma unroll
          for (int g = 0; g < 4; ++g)
            acc[g][mt] = __builtin_amdgcn_mfma_f32_16x16x32_bf16(wx[g], b, acc[g][mt], 0, 0, 0);
        }
      }

#pragma unroll
      for (int mt = 0; mt < 2; ++mt) {
        u64 pk = 0;
#pragma unroll
        for (int r = 0; r < 4; ++r) {
          const float iv = acc[0][mt][r], fv = acc[1][mt][r],
                      gv = acc[2][mt][r], ov = acc[3][mt][r];
          const float cn = sigm(fv) * creg[mt][r] + sigm(iv) * tanh_f(gv);
          creg[mt][r] = cn;
          const float hv = sigm(ov) * tanh_f(cn);
          pk |= (u64)f2bf(hv) << (16 * r);
        }
        const int batch = (wb * 2 + mt) * 16 + n16;
        astore(hexq + ((size_t)((t + 1) * 32 + kcq) * 64 + batch) * 2 + half, pk);
        astore(hcat64 + (size_t)(t * 64 + batch) * 128 + jq, pk);   // h-half
      }
      asm volatile("s_waitcnt vmcnt(0)" ::: "memory");
      __syncthreads();
      if (tid == 0)
        __hip_atomic_store(flags1 + bk, (unsigned)(t + 1),
                           __ATOMIC_RELAXED, __HIP_MEMORY_SCOPE_AGENT);
    }
  } else if (role < 1000) {
    // ============================ ATTN (one block per batch) ================
    const int b = role - 100;
    float* enc_s = (float*)smem;              // 73728 B
    float* h_s   = (float*)(smem + 73728);    // 1024 B
    float* at_s  = (float*)(smem + 74752);    // 288 B
    float* ctx_s = (float*)(smem + 75776);    // 1024 B
    const int wv8 = tid >> 6, ln = tid & 63;
    const int len = lens[b];
    const u64* hexq = (const u64*)hex;
    {
      const float4* src = (const float4*)(enc + (size_t)b * SS * HH);
      float4* dst = (float4*)enc_s;
      for (int i = tid; i < SS * HH / 4; i += 512) dst[i] = src[i];
    }
    __syncthreads();

    for (int t = 0; t < TT; ++t) {
      if (tid < NB) {
        while (__hip_atomic_load(flags1 + tid, __ATOMIC_RELAXED,
                                 __HIP_MEMORY_SCOPE_AGENT) < (unsigned)(t + 1))
          __builtin_amdgcn_s_sleep(1);
      }
      __syncthreads();
      if (tid < 64) {
        const int kc = tid >> 1, hf = tid & 1;
        const u64 v = aload(hexq + ((size_t)((t + 1) * 32 + kc) * 64 + b) * 2 + hf);
        const int j0 = kc * 8 + hf * 4;
        h_s[j0]     = bf2f((unsigned short)v);
        h_s[j0 + 1] = bf2f((unsigned short)(v >> 16));
        h_s[j0 + 2] = bf2f((unsigned short)(v >> 32));
        h_s[j0 + 3] = bf2f((unsigned short)(v >> 48));
      }
      __syncthreads();

      const float4 hv = ((const float4*)h_s)[ln];
      for (int s = wv8; s < SS; s += 8) {
        const float4 ev = ((const float4*)(enc_s + s * HH))[ln];
        float p = hv.x * ev.x + hv.y * ev.y + hv.z * ev.z + hv.w * ev.w;
        p = wsum(p);
        if (ln == 0) at_s[s] = p * 0.0625f;
      }
      __syncthreads();
      if (wv8 == 0) {
        const float v0 = (ln < len) ? at_s[ln] : -3.0e38f;
        const bool has1 = (ln < 8) && (64 + ln < len);
        const float v1 = has1 ? at_s[64 + ln] : -3.0e38f;
        const float m = wmax(fmaxf(v0, v1));
        const float e0 = (ln < len) ? __expf(v0 - m) : 0.f;
        const float e1 = has1 ? __expf(v1 - m) : 0.f;
        const float inv = 1.f / wsum(e0 + e1);
        at_s[ln] = e0 * inv;
        if (ln < 8) at_s[64 + ln] = e1 * inv;
      }
      __syncthreads();
      if (tid < HH) {
        float acc = 0.f;
#pragma unroll 8
        for (int s = 0; s < SS; ++s) acc += at_s[s] * enc_s[s * HH + tid];
        ctx_s[tid] = acc;
      }
      __syncthreads();
      if (tid < 64) {
        const u64 pk = (u64)f2bf(ctx_s[tid * 4])
                     | ((u64)f2bf(ctx_s[tid * 4 + 1]) << 16)
                     | ((u64)f2bf(ctx_s[tid * 4 + 2]) << 32)
                     | ((u64)f2bf(ctx_s[tid * 4 + 3]) << 48);
        astore(hcat64 + (size_t)(t * 64 + b) * 128 + 64 + tid, pk);
      }
      asm volatile("s_waitcnt vmcnt(0)" ::: "memory");
      __syncthreads();
      if (tid == 0)
        __hip_atomic_fetch_add(F2 + t, 1u, __ATOMIC_RELAXED, __HIP_MEMORY_SCOPE_AGENT);
    }
  } else {
    // ============================ GEMM (128x256 tile, 8 waves) ==============
    const int gid = role - 1000;
    unsigned short* As = (unsigned short*)smem;            // [128][32]
    unsigned short* Bs = (unsigned short*)(smem + 8192);   // [256][32]
    char* Asb = smem;
    char* Bsb = smem + 8192;
    const int ln = tid & 63, w = tid >> 6;
    const int n16 = ln & 15, kgrp = ln >> 4;
    const int wm = w >> 2, wn = w & 3;
    const int arow = tid >> 3, aq = tid & 7;
    const int o0 = tid * 16;
    const int r0 = o0 >> 6, c0b = o0 & 63;

    for (int it = gid; it < NITEM; it += NGEMM) {
      const int mc = it / NNT, ntile = it % NNT;
      if (tid == 0) {
        while (__hip_atomic_load(F2 + 2 * mc, __ATOMIC_RELAXED, __HIP_MEMORY_SCOPE_AGENT) < NATTN ||
               __hip_atomic_load(F2 + 2 * mc + 1, __ATOMIC_RELAXED, __HIP_MEMORY_SCOPE_AGENT) < NATTN)
          __builtin_amdgcn_s_sleep(2);
      }
      __syncthreads();

      const int m0 = mc * 128, n0 = ntile * 256;
      const char* Bb = (const char*)(wlin16 + (size_t)n0 * KK);
      f32x4 acc[4][4] = {};
      float bs[4];
#pragma unroll
      for (int fn = 0; fn < 4; ++fn) bs[fn] = blin[n0 + wn * 64 + fn * 16 + n16];

      for (int kt = 0; kt < 16; ++kt) {
        const u64 va0 = aload(hcat64 + (size_t)(m0 + arow) * 128 + kt * 8 + aq);
        const u64 va1 = aload(hcat64 + (size_t)(m0 + 64 + arow) * 128 + kt * 8 + aq);
        g2l16(Bb + (size_t)r0 * (KK * 2) + kt * 64 + c0b, Bsb + o0);
        g2l16(Bb + (size_t)(128 + r0) * (KK * 2) + kt * 64 + c0b, Bsb + 8192 + o0);
        asm volatile("s_waitcnt vmcnt(0)" ::: "memory");
        *(u64*)(Asb + arow * 64 + aq * 8) = va0;
        *(u64*)(Asb + 4096 + arow * 64 + aq * 8) = va1;
        __syncthreads();

        short8 af[4], bf[4];
#pragma unroll
        for (int f = 0; f < 4; ++f) {
          af[f] = *(const short8*)&As[(wm * 64 + f * 16 + n16) * 32 + kgrp * 8];
          bf[f] = *(const short8*)&Bs[(wn * 64 + f * 16 + n16) * 32 + kgrp * 8];
        }
#pragma unroll
        for (int fm = 0; fm < 4; ++fm)
#pragma unroll
          for (int fn = 0; fn < 4; ++fn)
            acc[fm][fn] = __builtin_amdgcn_mfma_f32_16x16x32_bf16(af[fm], bf[fn], acc[fm][fn], 0, 0, 0);
        __syncthreads();
      }

#pragma unroll
      for (int fm = 0; fm < 4; ++fm) {
        const int mrow = m0 + wm * 64 + fm * 16 + (ln >> 4) * 4;
        const int trow = mrow >> 6, brow = mrow & 63;
#pragma unroll
        for (int fn = 0; fn < 4; ++fn) {
          const int n = n0 + wn * 64 + fn * 16 + n16;
          float* cp = out + (size_t)(brow * TT + trow) * VV + n;
#pragma unroll
          for (int r = 0; r < 4; ++r) cp[(size_t)r * TT * VV] = acc[fm][fn][r] + bs[fn];
        }
      }
    }
  }
}

// ------------------------------------------------------------------
extern "C" void kernel_launch(void* const* d_in, const int* in_sizes, int n_in,
                              void* d_out, int out_size, void* d_ws, size_t ws_size,
                              hipStream_t stream) {
  const int*   tok  = (const int*)  d_in[0];
  const float* enc  = (const float*)d_in[1];
  const int*   lens = (const int*)  d_in[2];
  const float* h0   = (const float*)d_in[3];
  const float* c0   = (const float*)d_in[4];
  const float* emb  = (const float*)d_in[5];
  const float* Wih  = (const float*)d_in[6];
  const float* Whh  = (const float*)d_in[7];
  const float* bih  = (const float*)d_in[8];
  const float* bhh  = (const float*)d_in[9];
  const float* Wlin = (const float*)d_in[10];
  const float* blin = (const float*)d_in[11];

  char* ws = (char*)d_ws;
  unsigned short* wlin16 = (unsigned short*)(ws);               // 32,768,000 B
  u64*            hcat64 = (u64*)           (ws + 32768000);    //  4,718,592 B [t*64+b][128 u64]
  uint4*          xembt  = (uint4*)         (ws + 37486592);    //  1,179,648 B
  uint4*          hex    = (uint4*)         (ws + 38666240);    //  2,392,064 B
  unsigned int*   sync   = (unsigned int*)  (ws + 41058304);    //        512 B
  float* out = (float*)d_out;

  hipMemsetAsync(sync, 0, 512, stream);
  prep_kernel<<<256, 256, 0, stream>>>(tok, emb, Wlin, xembt, wlin16);
  mega_kernel<<<256, 512, 0, stream>>>(h0, c0, Wih, Whh, bih, bhh, enc, lens,
                                       blin, xembt, wlin16, hex, sync, hcat64, out);
}